// Round 6
// baseline (4371.371 us; speedup 1.0000x reference)
//
#include <hip/hip_runtime.h>
#include <hip/hip_bf16.h>
#include <hip/hip_fp16.h>
#include <cmath>

#define BB   8
#define CIN  8
#define TT   12
#define HH   128
#define WW   128
#define HID  32
#define CCOMB 40
#define HW   (HH * WW)
#define NBLK 1024

// LDS (u16 units): tile1 [180 px][40] @0 (x ch0..7, h ch8..39);
// tile2 (rh, co-based 0..31) [180][40] @7200; tileU fp16 [128][33] @14400;
// total 18624 u16 = 37,248 B -> 4 blocks/CU
#define S1   40
#define OFF2 7200
#define OFFU 14400
#define SMEM_U16 18624

typedef __attribute__((ext_vector_type(8))) short sv8;
typedef __attribute__((ext_vector_type(4))) short sv4;
typedef __attribute__((ext_vector_type(4))) float f32x4;
typedef unsigned short u16;

__device__ inline u16 f2bf(float f) {
    union { float f; unsigned u; } v; v.f = f;
    unsigned u = v.u;
    return (u16)((u + 0x7FFFu + ((u >> 16) & 1u)) >> 16);
}
__device__ inline float bf2f(u16 h) {
    union { unsigned u; float f; } v; v.u = ((unsigned)h) << 16; return v.f;
}
__device__ inline float sigmoid_fast(float x) { return 1.f / (1.f + __expf(-x)); }
__device__ inline float tanh_fast(float z) {
    float a = fabsf(z);
    float r = 1.f - 2.f / (__expf(2.f * a) + 1.f);
    return copysignf(r, z);
}

// ring px (52) of the 10x18 tile: index -> (r,c)
__device__ __forceinline__ void ring_rc(int i, int& r, int& c) {
    if (i < 18)      { r = 0;            c = i;       }
    else if (i < 36) { r = 9;            c = i - 18;  }
    else if (i < 44) { r = 1 + (i - 36); c = 0;       }
    else             { r = 1 + (i - 44); c = 17;      }
}

// monotonic grid barrier (all NBLK blocks co-resident by construction)
__device__ __forceinline__ void grid_barrier(unsigned* bar, unsigned target) {
    __syncthreads();
    if (threadIdx.x == 0) {
        __hip_atomic_fetch_add(bar, 1u, __ATOMIC_RELEASE, __HIP_MEMORY_SCOPE_AGENT);
        while (__hip_atomic_load(bar, __ATOMIC_ACQUIRE, __HIP_MEMORY_SCOPE_AGENT) < target)
            __builtin_amdgcn_s_sleep(2);
    }
    __syncthreads();
}

// ---------------------------------------------------------------------------
// weight pack: [Gall(6)][f=kx*4+ks (12)][lane(64)][8 bf16]
// ---------------------------------------------------------------------------
__device__ inline sv8 gather_wfrag(const float* __restrict__ W,
                                   int co, int g, int kx, int ks) {
    int k0 = ks * 32 + g * 8;
    sv8 f;
    if (k0 < 120) {
        int ky  = k0 / 40;
        int ci0 = k0 - ky * 40;
#pragma unroll
        for (int i = 0; i < 8; ++i)
            f[i] = (short)f2bf(W[(((size_t)co * CCOMB + ci0 + i) * 3 + ky) * 3 + kx]);
    } else {
#pragma unroll
        for (int i = 0; i < 8; ++i) f[i] = 0;
    }
    return f;
}

__global__ void pack_weights(const float* __restrict__ Wg,
                             const float* __restrict__ Wc,
                             u16* __restrict__ pack) {
    int tid = blockIdx.x * blockDim.x + threadIdx.x;
    if (tid >= 6 * 12 * 64) return;
    int lane = tid & 63;
    int f    = (tid >> 6) % 12;
    int Gall = tid / (12 * 64);
    int kx = f >> 2, ks = f & 3;
    int g = lane >> 4;
    sv8 v;
    if (Gall < 4) v = gather_wfrag(Wg, Gall * 16 + (lane & 15), g, kx, ks);
    else          v = gather_wfrag(Wc, (Gall - 4) * 16 + (lane & 15), g, kx, ks);
    *(sv8*)&pack[(size_t)tid * 8] = v;
}

__global__ __launch_bounds__(256) void x_to_bf16(const float* __restrict__ x,
                                                 u16* __restrict__ xbf) {
    int gid = blockIdx.x * 256 + threadIdx.x;
    if (gid >= BB * TT * HW) return;
    int p  = gid & (HW - 1);
    int bt = gid >> 14;
    int t = bt % TT, b = bt / TT;
    sv8 v;
#pragma unroll
    for (int c = 0; c < 8; ++c)
        v[c] = (short)f2bf(x[(((size_t)b * CIN + c) * TT + t) * HW + p]);
    *(sv8*)&xbf[(size_t)gid * 8] = v;
}

// ---------------------------------------------------------------------------
// Persistent GRU: 1024 blocks (4/CU), each owns a 16x8 tile for all T steps.
// h interior lives in LDS; only 1-px rings of h/rh cross blocks via global.
// ---------------------------------------------------------------------------
__global__ __launch_bounds__(256, 4) void gru_persist(
    const u16* __restrict__ xbf, const u16* __restrict__ wpack,
    const float* __restrict__ bg, const float* __restrict__ bc,
    u16* __restrict__ hG, u16* __restrict__ rhG,
    float* __restrict__ out, float* __restrict__ hlast,
    unsigned* __restrict__ bar)
{
    __shared__ __align__(16) u16 smem[SMEM_U16];
    const int id = blockIdx.x;
    const int b = id >> 7, by = (id >> 3) & 15, bx = id & 7;
    const int x0 = bx * 16, y0 = by * 8;
    const int tid = threadIdx.x, lane = tid & 63, w = tid >> 6;
    const int m = lane & 15, g = lane >> 4;

    int kyv[4], ci0v[4];
#pragma unroll
    for (int ks = 0; ks < 4; ++ks) {
        int k0 = ks * 32 + g * 8;
        kyv[ks] = 0; ci0v[ks] = 0;
        if (k0 < 120) { kyv[ks] = k0 / 40; ci0v[ks] = k0 - kyv[ks] * 40; }
    }

    // init all tile1 h slots to zero (h0 = 0)
    for (int i = tid; i < 720; i += 256) {
        int px = i >> 2, q = i & 3;
        sv8 z = {};
        *(sv8*)&smem[px * S1 + 8 + q * 8] = z;
    }

    const u16* xbB = xbf + (size_t)b * TT * HW * 8;
    u16* hGp  = hG  + (size_t)b * HW * 32;
    u16* rhGp = rhG + (size_t)b * HW * 32;

    const int co0g = w * 16 + g * 4;          // gates co group
    const int cg = w & 1, nh = w >> 1;        // cand co group / row half
    const int co0c = cg * 16 + g * 4;
    float biasg[4], biasc[4];
#pragma unroll
    for (int r = 0; r < 4; ++r) { biasg[r] = bg[co0g + r]; biasc[r] = bc[co0c + r]; }

    unsigned nbar = 0;

    for (int t = 0; t < TT; ++t) {
        // ======== phase A: stage x (all 180 px) + h ring (52 px) ========
        const u16* xb = xbB + (size_t)t * HW * 8;
        if (tid < 180) {
            int r = tid / 18, c = tid - r * 18;
            int gy = y0 - 1 + r, gx = x0 - 1 + c;
            sv8 v = {};
            if ((unsigned)gy < 128u && (unsigned)gx < 128u)
                v = *(const sv8*)&xb[(size_t)(gy * WW + gx) * 8];
            *(sv8*)&smem[tid * S1] = v;
        }
        if (tid < 208) {
            int pi = tid >> 2, q = tid & 3;
            int r, c; ring_rc(pi, r, c);
            int gy = y0 - 1 + r, gx = x0 - 1 + c;
            sv8 v = {};
            if ((unsigned)gy < 128u && (unsigned)gx < 128u)
                v = *(const sv8*)&hGp[(size_t)(gy * WW + gx) * 32 + q * 8];
            *(sv8*)&smem[(r * 18 + c) * S1 + 8 + q * 8] = v;
        }
        __syncthreads();

        // ---- gates conv: 8 N-tiles x 12 frags ----
        f32x4 acc[8];
#pragma unroll
        for (int j = 0; j < 8; ++j) acc[j] = (f32x4){0.f, 0.f, 0.f, 0.f};
#pragma unroll
        for (int kx = 0; kx < 3; ++kx) {
            sv8 wf[4];
#pragma unroll
            for (int ks = 0; ks < 4; ++ks)
                wf[ks] = *(const sv8*)&wpack[(((size_t)w * 12 + kx * 4 + ks) * 64 + lane) * 8];
#pragma unroll
            for (int ks = 0; ks < 4; ++ks)
#pragma unroll
                for (int j = 0; j < 8; ++j) {
                    sv8 bv = *(const sv8*)&smem[((j + kyv[ks]) * 18 + m + kx) * S1 + ci0v[ks]];
                    acc[j] = __builtin_amdgcn_mfma_f32_16x16x32_bf16(wf[ks], bv, acc[j], 0, 0, 0);
                }
        }

        // ---- epilogue A ----
        if (w < 2) {   // reset gates: rh -> tile2 interior (co-based 0..31)
#pragma unroll
            for (int j = 0; j < 8; ++j) {
                int ctr = ((j + 1) * 18 + m + 1) * S1;
                sv4 h4 = *(const sv4*)&smem[ctr + 8 + co0g];
                sv4 rh4;
#pragma unroll
                for (int r = 0; r < 4; ++r) {
                    float gv = sigmoid_fast(acc[j][r] + biasg[r]);
                    rh4[r] = (short)f2bf(gv * bf2f((u16)h4[r]));
                }
                *(sv4*)&smem[OFF2 + ctr + co0g] = rh4;
                if (j == 0 || j == 7 || m == 0 || m == 15) {
                    int gy = y0 + j, gx = x0 + m;
                    *(sv4*)&rhGp[(size_t)(gy * WW + gx) * 32 + co0g] = rh4;
                }
            }
        } else {       // update gates -> tileU (fp16)
            int u0 = co0g - 32;
#pragma unroll
            for (int j = 0; j < 8; ++j) {
                int ub = OFFU + (j * 16 + m) * 33 + u0;
#pragma unroll
                for (int r = 0; r < 4; ++r)
                    smem[ub + r] = __half_as_ushort(__float2half(sigmoid_fast(acc[j][r] + biasg[r])));
            }
        }

        nbar += 1; grid_barrier(bar, nbar * NBLK);

        // ======== phase B: stage rh ring (co-based 0..31), cand conv + blend ========
        if (tid < 208) {
            int pi = tid >> 2, q = tid & 3;
            int r, c; ring_rc(pi, r, c);
            int gy = y0 - 1 + r, gx = x0 - 1 + c;
            sv8 v = {};
            if ((unsigned)gy < 128u && (unsigned)gx < 128u)
                v = *(const sv8*)&rhGp[(size_t)(gy * WW + gx) * 32 + q * 8];
            *(sv8*)&smem[OFF2 + (r * 18 + c) * S1 + q * 8] = v;   // FIX: co-based
        }
        __syncthreads();

        int off_k[4];
#pragma unroll
        for (int ks = 0; ks < 4; ++ks)
            off_k[ks] = (ci0v[ks] == 0) ? 0 : (OFF2 + (ci0v[ks] - 8));  // FIX: co-based

        f32x4 a2[4];
#pragma unroll
        for (int k2 = 0; k2 < 4; ++k2) a2[k2] = (f32x4){0.f, 0.f, 0.f, 0.f};
#pragma unroll
        for (int kx = 0; kx < 3; ++kx) {
            sv8 wc[4];
#pragma unroll
            for (int ks = 0; ks < 4; ++ks)
                wc[ks] = *(const sv8*)&wpack[(((size_t)(4 + cg) * 12 + kx * 4 + ks) * 64 + lane) * 8];
#pragma unroll
            for (int ks = 0; ks < 4; ++ks)
#pragma unroll
                for (int k2 = 0; k2 < 4; ++k2) {
                    int j = nh * 4 + k2;
                    sv8 bv = *(const sv8*)&smem[((j + kyv[ks]) * 18 + m + kx) * S1 + off_k[ks]];
                    a2[k2] = __builtin_amdgcn_mfma_f32_16x16x32_bf16(wc[ks], bv, a2[k2], 0, 0, 0);
                }
        }

#pragma unroll
        for (int k2 = 0; k2 < 4; ++k2) {
            int j = nh * 4 + k2;
            int gy = y0 + j, gx = x0 + m;
            int ctr = ((j + 1) * 18 + m + 1) * S1;
            sv4 h4 = *(const sv4*)&smem[ctr + 8 + co0c];
            int ub = OFFU + (j * 16 + m) * 33 + co0c;
            sv4 hn4;
#pragma unroll
            for (int r = 0; r < 4; ++r) {
                float cv   = tanh_fast(a2[k2][r] + biasc[r]);
                float uu   = __half2float(__ushort_as_half(smem[ub + r]));
                float hold = bf2f((u16)h4[r]);
                float hn = (1.f - uu) * hold + uu * cv;
                out[(((size_t)b * HID + co0c + r) * TT + t) * HW + (size_t)gy * WW + gx] = hn;
                hn4[r] = (short)f2bf(hn);
                if (t == TT - 1)
                    hlast[((size_t)b * HID + co0c + r) * HW + (size_t)gy * WW + gx] = hn;
            }
            *(sv4*)&smem[ctr + 8 + co0c] = hn4;   // update LDS-resident h
            if (j == 0 || j == 7 || m == 0 || m == 15)
                *(sv4*)&hGp[(size_t)(gy * WW + gx) * 32 + co0c] = hn4;
        }

        nbar += 1; grid_barrier(bar, nbar * NBLK);
    }
}

extern "C" void kernel_launch(void* const* d_in, const int* in_sizes, int n_in,
                              void* d_out, int out_size, void* d_ws, size_t ws_size,
                              hipStream_t stream) {
    const float* x  = (const float*)d_in[0];
    const float* Wg = (const float*)d_in[1];
    const float* bg = (const float*)d_in[2];
    const float* Wc = (const float*)d_in[3];
    const float* bc = (const float*)d_in[4];

    float* out   = (float*)d_out;
    float* hlast = out + (size_t)BB * HID * TT * HW;

    const size_t PLANE = (size_t)BB * HW * 32 * sizeof(u16);     // 8.39 MB
    const size_t PACKB = (size_t)6 * 12 * 64 * 8 * sizeof(u16);  // 73.7 KB
    char* ws = (char*)d_ws;
    u16* hG    = (u16*)ws;
    u16* rhG   = (u16*)(ws + PLANE);
    u16* wpack = (u16*)(ws + 2 * PLANE);
    unsigned* bar = (unsigned*)(ws + 2 * PLANE + PACKB);
    u16* xbf   = (u16*)(ws + 2 * PLANE + PACKB + 256);

    pack_weights<<<(6 * 12 * 64 + 255) / 256, 256, 0, stream>>>(Wg, Wc, wpack);
    x_to_bf16<<<(BB * TT * HW) / 256, 256, 0, stream>>>(x, xbf);
    hipMemsetAsync(hG, 0, PLANE, stream);
    hipMemsetAsync(bar, 0, 256, stream);

    gru_persist<<<NBLK, 256, 0, stream>>>(xbf, wpack, bg, bc, hG, rhG,
                                          out, hlast, bar);
}

// Round 7
// 2165.335 us; speedup vs baseline: 2.0188x; 2.0188x over previous
//
#include <hip/hip_runtime.h>
#include <hip/hip_bf16.h>
#include <hip/hip_fp16.h>
#include <cmath>

#define BB   8
#define CIN  8
#define TT   12
#define HH   128
#define WW   128
#define HID  32
#define CCOMB 40
#define HW   (HH * WW)
#define NBLK 1024

// LDS (u16 units): tile1 [12x20 px][40] @0 (x ch0..7, h ch8..39);
// tile2 (rh, co 0..31) [10x18 px][36] @9600 ; tileU fp16 [128][33] @16080
// total 20304 u16 = 40,608 B  -> 4 blocks/CU (162,432 <= 163,840)
#define S1    40
#define T1W   20
#define OFF2  9600
#define S2    36
#define OFFU  16080
#define SMEM_U16 20304

typedef __attribute__((ext_vector_type(8))) short sv8;
typedef __attribute__((ext_vector_type(4))) short sv4;
typedef __attribute__((ext_vector_type(4))) float f32x4;
typedef unsigned short u16;

__device__ inline u16 f2bf(float f) {
    union { float f; unsigned u; } v; v.f = f;
    unsigned u = v.u;
    return (u16)((u + 0x7FFFu + ((u >> 16) & 1u)) >> 16);
}
__device__ inline float bf2f(u16 h) {
    union { unsigned u; float f; } v; v.u = ((unsigned)h) << 16; return v.f;
}
__device__ inline float sigmoid_fast(float x) { return 1.f / (1.f + __expf(-x)); }
__device__ inline float tanh_fast(float z) {
    float a = fabsf(z);
    float r = 1.f - 2.f / (__expf(2.f * a) + 1.f);
    return copysignf(r, z);
}

// 2-px border band of the 12x20 tile (112 px): i -> (r,c)
__device__ __forceinline__ void band_rc(int i, int& r, int& c) {
    if (i < 40)      { r = i / 20;            c = i % 20; }            // rows 0,1
    else if (i < 80) { int j = i - 40; r = 10 + j / 20; c = j % 20; }  // rows 10,11
    else             { int j = i - 80; r = 2 + (j >> 2);
                       int k = j & 3;  c = (k < 2) ? k : 16 + k; }     // cols 0,1,18,19
}

// ---------------------------------------------------------------------------
// weight pack: [Gall(6)][f=kx*4+ks (12)][lane(64)][8 bf16]
// ---------------------------------------------------------------------------
__device__ inline sv8 gather_wfrag(const float* __restrict__ W,
                                   int co, int g, int kx, int ks) {
    int k0 = ks * 32 + g * 8;
    sv8 f;
    if (k0 < 120) {
        int ky  = k0 / 40;
        int ci0 = k0 - ky * 40;
#pragma unroll
        for (int i = 0; i < 8; ++i)
            f[i] = (short)f2bf(W[(((size_t)co * CCOMB + ci0 + i) * 3 + ky) * 3 + kx]);
    } else {
#pragma unroll
        for (int i = 0; i < 8; ++i) f[i] = 0;
    }
    return f;
}

__global__ void pack_weights(const float* __restrict__ Wg,
                             const float* __restrict__ Wc,
                             u16* __restrict__ pack) {
    int tid = blockIdx.x * blockDim.x + threadIdx.x;
    if (tid >= 6 * 12 * 64) return;
    int lane = tid & 63;
    int f    = (tid >> 6) % 12;
    int Gall = tid / (12 * 64);
    int kx = f >> 2, ks = f & 3;
    int g = lane >> 4;
    sv8 v;
    if (Gall < 4) v = gather_wfrag(Wg, Gall * 16 + (lane & 15), g, kx, ks);
    else          v = gather_wfrag(Wc, (Gall - 4) * 16 + (lane & 15), g, kx, ks);
    *(sv8*)&pack[(size_t)tid * 8] = v;
}

__global__ __launch_bounds__(256) void x_to_bf16(const float* __restrict__ x,
                                                 u16* __restrict__ xbf) {
    int gid = blockIdx.x * 256 + threadIdx.x;
    if (gid >= BB * TT * HW) return;
    int p  = gid & (HW - 1);
    int bt = gid >> 14;
    int t = bt % TT, b = bt / TT;
    sv8 v;
#pragma unroll
    for (int c = 0; c < 8; ++c)
        v[c] = (short)f2bf(x[(((size_t)b * CIN + c) * TT + t) * HW + p]);
    *(sv8*)&xbf[(size_t)gid * 8] = v;
}

// ---------------------------------------------------------------------------
// Persistent GRU, p2p neighbor sync, 1 sync/step.
// id = tau*8 + b (b = image = XCD under round-robin); tau = by*8 + bx.
// Per step: stage x + 2px h-band (plane t&1) -> gates over 18x10 (rh, u in
// LDS) -> cand over 16x8 -> blend; write h-band (plane (t+1)&1); post flag.
// ---------------------------------------------------------------------------
__global__ __launch_bounds__(256, 4) void gru_persist(
    const u16* __restrict__ xbf, const u16* __restrict__ wpack,
    const float* __restrict__ bg, const float* __restrict__ bc,
    u16* __restrict__ hG, int* __restrict__ flags,
    float* __restrict__ out, float* __restrict__ hlast)
{
    __shared__ __align__(16) u16 smem[SMEM_U16];
    const int id = blockIdx.x;
    const int b = id & 7, tau = id >> 3;
    const int bx = tau & 7, by = tau >> 3;
    const int x0 = bx * 16, y0 = by * 8;
    const int tid = threadIdx.x, lane = tid & 63, w = tid >> 6;
    const int m = lane & 15, g = lane >> 4;

    // neighbor ids (8 dirs), -1 if outside image
    int nbr = -1;
    if (tid < 8) {
        const int dxs[8] = {-1, 0, 1, -1, 1, -1, 0, 1};
        const int dys[8] = {-1, -1, -1, 0, 0, 1, 1, 1};
        int nx = bx + dxs[tid], ny = by + dys[tid];
        if ((unsigned)nx < 8u && (unsigned)ny < 16u)
            nbr = ((ny * 8 + nx) * 8 + b);
    }

    int kyv[4], ci0v[4];
#pragma unroll
    for (int ks = 0; ks < 4; ++ks) {
        int k0 = ks * 32 + g * 8;
        kyv[ks] = 0; ci0v[ks] = 0;
        if (k0 < 120) { kyv[ks] = k0 / 40; ci0v[ks] = k0 - kyv[ks] * 40; }
    }

    // zero all tile1 h slots (h0 = 0)
    for (int i = tid; i < 960; i += 256) {
        int px = i >> 2, q = i & 3;
        sv8 z = {};
        *(sv8*)&smem[px * S1 + 8 + q * 8] = z;
    }

    const u16* xbB = xbf + (size_t)b * TT * HW * 8;
    const size_t planeElems = (size_t)BB * HW * 32;

    const int co0g = w * 16 + g * 4;          // gates co group
    const int cg = w & 1, nh = w >> 1;        // cand co group / row half
    const int co0c = cg * 16 + g * 4;
    float biasg[4], biasc[4];
#pragma unroll
    for (int r = 0; r < 4; ++r) { biasg[r] = bg[co0g + r]; biasc[r] = bc[co0c + r]; }

    for (int t = 0; t < TT; ++t) {
        const u16* hGr = hG + (size_t)(t & 1) * planeElems + (size_t)b * HW * 32;
        u16*       hGw = hG + (size_t)((t + 1) & 1) * planeElems + (size_t)b * HW * 32;

        // ---- stage x (240 px) — independent of neighbor progress ----
        const u16* xb = xbB + (size_t)t * HW * 8;
        if (tid < 240) {
            int r = tid / 20, c = tid - r * 20;
            int gy = y0 + r - 2, gx = x0 + c - 2;
            sv8 v = {};
            if ((unsigned)gy < 128u && (unsigned)gx < 128u)
                v = *(const sv8*)&xb[(size_t)(gy * WW + gx) * 8];
            *(sv8*)&smem[tid * S1] = v;
        }

        // ---- wait for neighbors to finish step t-1 ----
        if (t > 0) {
            if (tid < 8 && nbr >= 0) {
                while (__hip_atomic_load(&flags[nbr * 32], __ATOMIC_RELAXED,
                                         __HIP_MEMORY_SCOPE_AGENT) < t)
                    __builtin_amdgcn_s_sleep(8);
            }
            __syncthreads();
            __builtin_amdgcn_fence(__ATOMIC_ACQUIRE, "agent");
        }

        // ---- stage h band (112 px x 32ch) from plane t&1 ----
        for (int idx = tid; idx < 112 * 4; idx += 256) {
            int i = idx >> 2, q = idx & 3;
            int r, c; band_rc(i, r, c);
            int gy = y0 + r - 2, gx = x0 + c - 2;
            sv8 v = {};
            if ((unsigned)gy < 128u && (unsigned)gx < 128u)
                v = *(const sv8*)&hGr[(size_t)(gy * WW + gx) * 32 + q * 8];
            *(sv8*)&smem[(r * T1W + c) * S1 + 8 + q * 8] = v;
        }
        __syncthreads();

        // ---- gates conv over 18x10 region (180 px = 12 groups), 2 halves ----
#pragma unroll
        for (int half = 0; half < 2; ++half) {
            int yyv[6], xxv[6];
#pragma unroll
            for (int jj = 0; jj < 6; ++jj) {
                int p2 = (half * 6 + jj) * 16 + m;
                int px = (p2 < 180) ? p2 : 179;
                yyv[jj] = px / 18; xxv[jj] = px - yyv[jj] * 18;
            }
            f32x4 acc[6];
#pragma unroll
            for (int jj = 0; jj < 6; ++jj) acc[jj] = (f32x4){0.f, 0.f, 0.f, 0.f};
#pragma unroll
            for (int kx = 0; kx < 3; ++kx) {
                sv8 wf[4];
#pragma unroll
                for (int ks = 0; ks < 4; ++ks)
                    wf[ks] = *(const sv8*)&wpack[(((size_t)w * 12 + kx * 4 + ks) * 64 + lane) * 8];
#pragma unroll
                for (int ks = 0; ks < 4; ++ks)
#pragma unroll
                    for (int jj = 0; jj < 6; ++jj) {
                        sv8 bv = *(const sv8*)&smem[((yyv[jj] + kyv[ks]) * T1W + xxv[jj] + kx) * S1 + ci0v[ks]];
                        acc[jj] = __builtin_amdgcn_mfma_f32_16x16x32_bf16(wf[ks], bv, acc[jj], 0, 0, 0);
                    }
            }
            // epilogue A
            if (w < 2) {       // reset -> rh into tile2 (LDS only)
#pragma unroll
                for (int jj = 0; jj < 6; ++jj) {
                    int p2 = (half * 6 + jj) * 16 + m;
                    int yy = yyv[jj], xx = xxv[jj];
                    sv4 h4 = *(const sv4*)&smem[((yy + 1) * T1W + xx + 1) * S1 + 8 + co0g];
                    sv4 rh4;
#pragma unroll
                    for (int r = 0; r < 4; ++r) {
                        float gv = sigmoid_fast(acc[jj][r] + biasg[r]);
                        rh4[r] = (short)f2bf(gv * bf2f((u16)h4[r]));
                    }
                    if (p2 < 180)
                        *(sv4*)&smem[OFF2 + (yy * 18 + xx) * S2 + co0g] = rh4;
                }
            } else {           // update -> tileU (interior only)
                int u0 = co0g - 32;
#pragma unroll
                for (int jj = 0; jj < 6; ++jj) {
                    int p2 = (half * 6 + jj) * 16 + m;
                    int yy = yyv[jj], xx = xxv[jj];
                    u16 uv[4];
#pragma unroll
                    for (int r = 0; r < 4; ++r)
                        uv[r] = __half_as_ushort(__float2half(sigmoid_fast(acc[jj][r] + biasg[r])));
                    if (p2 < 180 && yy >= 1 && yy <= 8 && xx >= 1 && xx <= 16) {
                        int ub = OFFU + ((yy - 1) * 16 + (xx - 1)) * 33 + u0;
                        smem[ub] = uv[0]; smem[ub + 1] = uv[1];
                        smem[ub + 2] = uv[2]; smem[ub + 3] = uv[3];
                    }
                }
            }
        }
        __syncthreads();

        // ---- cand conv over interior 16x8 (4 rows per wave) + blend ----
        f32x4 a2[4];
#pragma unroll
        for (int k2 = 0; k2 < 4; ++k2) a2[k2] = (f32x4){0.f, 0.f, 0.f, 0.f};
#pragma unroll
        for (int kx = 0; kx < 3; ++kx) {
            sv8 wc[4];
#pragma unroll
            for (int ks = 0; ks < 4; ++ks)
                wc[ks] = *(const sv8*)&wpack[(((size_t)(4 + cg) * 12 + kx * 4 + ks) * 64 + lane) * 8];
#pragma unroll
            for (int ks = 0; ks < 4; ++ks)
#pragma unroll
                for (int k2 = 0; k2 < 4; ++k2) {
                    int j = nh * 4 + k2;
                    int a_x  = ((j + 1 + kyv[ks]) * T1W + m + 1 + kx) * S1;
                    int a_rh = OFF2 + ((j + kyv[ks]) * 18 + m + kx) * S2 + (ci0v[ks] - 8);
                    int addr = (ci0v[ks] == 0) ? a_x : a_rh;
                    sv4 lo = *(const sv4*)&smem[addr];
                    sv4 hi = *(const sv4*)&smem[addr + 4];
                    sv8 bv = __builtin_shufflevector(lo, hi, 0, 1, 2, 3, 4, 5, 6, 7);
                    a2[k2] = __builtin_amdgcn_mfma_f32_16x16x32_bf16(wc[ks], bv, a2[k2], 0, 0, 0);
                }
        }

#pragma unroll
        for (int k2 = 0; k2 < 4; ++k2) {
            int j = nh * 4 + k2;
            int gy = y0 + j, gx = x0 + m;
            int ctr = ((j + 2) * T1W + m + 2) * S1;
            sv4 h4 = *(const sv4*)&smem[ctr + 8 + co0c];
            int ub = OFFU + (j * 16 + m) * 33 + co0c;
            sv4 hn4;
#pragma unroll
            for (int r = 0; r < 4; ++r) {
                float cv   = tanh_fast(a2[k2][r] + biasc[r]);
                float uu   = __half2float(__ushort_as_half(smem[ub + r]));
                float hold = bf2f((u16)h4[r]);
                float hn = (1.f - uu) * hold + uu * cv;
                out[(((size_t)b * HID + co0c + r) * TT + t) * HW + (size_t)gy * WW + gx] = hn;
                hn4[r] = (short)f2bf(hn);
                if (t == TT - 1)
                    hlast[((size_t)b * HID + co0c + r) * HW + (size_t)gy * WW + gx] = hn;
            }
            *(sv4*)&smem[ctr + 8 + co0c] = hn4;   // persist h in LDS
            // 2-px interior border -> hG plane (t+1)&1 for neighbors
            if (j <= 1 || j >= 6 || m <= 1 || m >= 14)
                *(sv4*)&hGw[(size_t)(gy * WW + gx) * 32 + co0c] = hn4;
        }

        __syncthreads();
        if (tid == 0) {
            __builtin_amdgcn_fence(__ATOMIC_RELEASE, "agent");
            __hip_atomic_store(&flags[id * 32], t + 1, __ATOMIC_RELAXED,
                               __HIP_MEMORY_SCOPE_AGENT);
        }
    }
}

extern "C" void kernel_launch(void* const* d_in, const int* in_sizes, int n_in,
                              void* d_out, int out_size, void* d_ws, size_t ws_size,
                              hipStream_t stream) {
    const float* x  = (const float*)d_in[0];
    const float* Wg = (const float*)d_in[1];
    const float* bg = (const float*)d_in[2];
    const float* Wc = (const float*)d_in[3];
    const float* bc = (const float*)d_in[4];

    float* out   = (float*)d_out;
    float* hlast = out + (size_t)BB * HID * TT * HW;

    const size_t PLANEB = (size_t)BB * HW * 32 * sizeof(u16);    // 8.39 MB
    const size_t PACKB  = (size_t)6 * 12 * 64 * 8 * sizeof(u16); // 73.7 KB
    const size_t FLAGB  = (size_t)NBLK * 32 * sizeof(int);       // 128 KB
    char* ws = (char*)d_ws;
    u16* hG    = (u16*)ws;                        // 2 planes
    u16* wpack = (u16*)(ws + 2 * PLANEB);
    int* flags = (int*)(ws + 2 * PLANEB + PACKB);
    u16* xbf   = (u16*)(ws + 2 * PLANEB + PACKB + FLAGB);

    pack_weights<<<(6 * 12 * 64 + 255) / 256, 256, 0, stream>>>(Wg, Wc, wpack);
    x_to_bf16<<<(BB * TT * HW) / 256, 256, 0, stream>>>(x, xbf);
    hipMemsetAsync(hG, 0, PLANEB, stream);        // plane 0 = h0 = 0
    hipMemsetAsync(flags, 0, FLAGB, stream);

    gru_persist<<<NBLK, 256, 0, stream>>>(xbf, wpack, bg, bc, hG, flags,
                                          out, hlast);
}

// Round 8
// 1525.013 us; speedup vs baseline: 2.8664x; 1.4199x over previous
//
#include <hip/hip_runtime.h>
#include <hip/hip_bf16.h>
#include <hip/hip_fp16.h>
#include <cmath>

#define BB   8
#define CIN  8
#define TT   12
#define HH   128
#define WW   128
#define HID  32
#define CCOMB 40
#define HW   (HH * WW)
#define NBLK 1024

// LDS (u16 units): tile1 [12x20 px][40] @0 (x ch0..7, h ch8..39);
// tile2 (rh, co 0..31) [10x18 px][36] @9600 ; tileU fp16 [128][33] @16080
// total 20304 u16 = 40,608 B  -> 4 blocks/CU (162,432 <= 163,840)
#define S1    40
#define T1W   20
#define OFF2  9600
#define S2    36
#define OFFU  16080
#define SMEM_U16 20304

typedef __attribute__((ext_vector_type(8))) short sv8;
typedef __attribute__((ext_vector_type(4))) short sv4;
typedef __attribute__((ext_vector_type(4))) float f32x4;
typedef unsigned short u16;
typedef unsigned long long ull;

__device__ inline u16 f2bf(float f) {
    union { float f; unsigned u; } v; v.f = f;
    unsigned u = v.u;
    return (u16)((u + 0x7FFFu + ((u >> 16) & 1u)) >> 16);
}
__device__ inline float bf2f(u16 h) {
    union { unsigned u; float f; } v; v.u = ((unsigned)h) << 16; return v.f;
}
__device__ inline float sigmoid_fast(float x) { return 1.f / (1.f + __expf(-x)); }
__device__ inline float tanh_fast(float z) {
    float a = fabsf(z);
    float r = 1.f - 2.f / (__expf(2.f * a) + 1.f);
    return copysignf(r, z);
}

// 2-px border band of the 12x20 tile (112 px): i -> (r,c)
__device__ __forceinline__ void band_rc(int i, int& r, int& c) {
    if (i < 40)      { r = i / 20;            c = i % 20; }            // rows 0,1
    else if (i < 80) { int j = i - 40; r = 10 + j / 20; c = j % 20; }  // rows 10,11
    else             { int j = i - 80; r = 2 + (j >> 2);
                       int k = j & 3;  c = (k < 2) ? k : 16 + k; }     // cols 0,1,18,19
}

// ---------------------------------------------------------------------------
// weight pack: [Gall(6)][f=kx*4+ks (12)][lane(64)][8 bf16]
// ---------------------------------------------------------------------------
__device__ inline sv8 gather_wfrag(const float* __restrict__ W,
                                   int co, int g, int kx, int ks) {
    int k0 = ks * 32 + g * 8;
    sv8 f;
    if (k0 < 120) {
        int ky  = k0 / 40;
        int ci0 = k0 - ky * 40;
#pragma unroll
        for (int i = 0; i < 8; ++i)
            f[i] = (short)f2bf(W[(((size_t)co * CCOMB + ci0 + i) * 3 + ky) * 3 + kx]);
    } else {
#pragma unroll
        for (int i = 0; i < 8; ++i) f[i] = 0;
    }
    return f;
}

__global__ void pack_weights(const float* __restrict__ Wg,
                             const float* __restrict__ Wc,
                             u16* __restrict__ pack) {
    int tid = blockIdx.x * blockDim.x + threadIdx.x;
    if (tid >= 6 * 12 * 64) return;
    int lane = tid & 63;
    int f    = (tid >> 6) % 12;
    int Gall = tid / (12 * 64);
    int kx = f >> 2, ks = f & 3;
    int g = lane >> 4;
    sv8 v;
    if (Gall < 4) v = gather_wfrag(Wg, Gall * 16 + (lane & 15), g, kx, ks);
    else          v = gather_wfrag(Wc, (Gall - 4) * 16 + (lane & 15), g, kx, ks);
    *(sv8*)&pack[(size_t)tid * 8] = v;
}

__global__ __launch_bounds__(256) void x_to_bf16(const float* __restrict__ x,
                                                 u16* __restrict__ xbf) {
    int gid = blockIdx.x * 256 + threadIdx.x;
    if (gid >= BB * TT * HW) return;
    int p  = gid & (HW - 1);
    int bt = gid >> 14;
    int t = bt % TT, b = bt / TT;
    sv8 v;
#pragma unroll
    for (int c = 0; c < 8; ++c)
        v[c] = (short)f2bf(x[(((size_t)b * CIN + c) * TT + t) * HW + p]);
    *(sv8*)&xbf[(size_t)gid * 8] = v;
}

// ---------------------------------------------------------------------------
// Persistent GRU, p2p neighbor sync, FENCE-FREE message passing:
// all cross-block data moves via device-scope relaxed atomics (coherence
// point), so caches are never invalidated. One sync per step.
// ---------------------------------------------------------------------------
__global__ __launch_bounds__(256, 4) void gru_persist(
    const u16* __restrict__ xbf, const u16* __restrict__ wpack,
    const float* __restrict__ bg, const float* __restrict__ bc,
    u16* __restrict__ hG, int* __restrict__ flags,
    float* __restrict__ out, float* __restrict__ hlast)
{
    __shared__ __align__(16) u16 smem[SMEM_U16];
    const int id = blockIdx.x;
    const int b = id & 7, tau = id >> 3;
    const int bx = tau & 7, by = tau >> 3;
    const int x0 = bx * 16, y0 = by * 8;
    const int tid = threadIdx.x, lane = tid & 63, w = tid >> 6;
    const int m = lane & 15, g = lane >> 4;

    // neighbor ids (8 dirs), -1 if outside image
    int nbr = -1;
    if (tid < 8) {
        const int dxs[8] = {-1, 0, 1, -1, 1, -1, 0, 1};
        const int dys[8] = {-1, -1, -1, 0, 0, 1, 1, 1};
        int nx = bx + dxs[tid], ny = by + dys[tid];
        if ((unsigned)nx < 8u && (unsigned)ny < 16u)
            nbr = ((ny * 8 + nx) * 8 + b);
    }

    int kyv[4], ci0v[4];
#pragma unroll
    for (int ks = 0; ks < 4; ++ks) {
        int k0 = ks * 32 + g * 8;
        kyv[ks] = 0; ci0v[ks] = 0;
        if (k0 < 120) { kyv[ks] = k0 / 40; ci0v[ks] = k0 - kyv[ks] * 40; }
    }

    // zero all tile1 h slots (h0 = 0)
    for (int i = tid; i < 960; i += 256) {
        int px = i >> 2, q = i & 3;
        sv8 z = {};
        *(sv8*)&smem[px * S1 + 8 + q * 8] = z;
    }

    const u16* xbB = xbf + (size_t)b * TT * HW * 8;
    const size_t planeElems = (size_t)BB * HW * 32;

    const int co0g = w * 16 + g * 4;          // gates co group
    const int cg = w & 1, nh = w >> 1;        // cand co group / row half
    const int co0c = cg * 16 + g * 4;
    float biasg[4], biasc[4];
#pragma unroll
    for (int r = 0; r < 4; ++r) { biasg[r] = bg[co0g + r]; biasc[r] = bc[co0c + r]; }

    for (int t = 0; t < TT; ++t) {
        const u16* hGr = hG + (size_t)(t & 1) * planeElems + (size_t)b * HW * 32;
        u16*       hGw = hG + (size_t)((t + 1) & 1) * planeElems + (size_t)b * HW * 32;

        // ---- stage x (240 px) — independent of neighbor progress ----
        const u16* xb = xbB + (size_t)t * HW * 8;
        if (tid < 240) {
            int r = tid / 20, c = tid - r * 20;
            int gy = y0 + r - 2, gx = x0 + c - 2;
            sv8 v = {};
            if ((unsigned)gy < 128u && (unsigned)gx < 128u)
                v = *(const sv8*)&xb[(size_t)(gy * WW + gx) * 8];
            *(sv8*)&smem[tid * S1] = v;
        }

        // ---- wait for neighbors to finish step t-1 (no fence needed) ----
        if (t > 0) {
            if (tid < 8 && nbr >= 0) {
                while (__hip_atomic_load(&flags[nbr * 32], __ATOMIC_RELAXED,
                                         __HIP_MEMORY_SCOPE_AGENT) < t)
                    __builtin_amdgcn_s_sleep(32);
            }
            __syncthreads();
        }

        // ---- stage h band (112 px x 32ch) via 8B relaxed atomics ----
        for (int idx = tid; idx < 112 * 8; idx += 256) {
            int i = idx >> 3, q = idx & 7;
            int r, c; band_rc(i, r, c);
            int gy = y0 + r - 2, gx = x0 + c - 2;
            ull v = 0;
            if ((unsigned)gy < 128u && (unsigned)gx < 128u)
                v = __hip_atomic_load((const ull*)&hGr[(size_t)(gy * WW + gx) * 32 + q * 4],
                                      __ATOMIC_RELAXED, __HIP_MEMORY_SCOPE_AGENT);
            *(ull*)&smem[(r * T1W + c) * S1 + 8 + q * 4] = v;
        }
        __syncthreads();

        // ---- gates conv over 18x10 region (180 px = 12 groups), 2 halves ----
#pragma unroll
        for (int half = 0; half < 2; ++half) {
            int yyv[6], xxv[6];
#pragma unroll
            for (int jj = 0; jj < 6; ++jj) {
                int p2 = (half * 6 + jj) * 16 + m;
                int px = (p2 < 180) ? p2 : 179;
                yyv[jj] = px / 18; xxv[jj] = px - yyv[jj] * 18;
            }
            f32x4 acc[6];
#pragma unroll
            for (int jj = 0; jj < 6; ++jj) acc[jj] = (f32x4){0.f, 0.f, 0.f, 0.f};
#pragma unroll
            for (int kx = 0; kx < 3; ++kx) {
                sv8 wf[4];
#pragma unroll
                for (int ks = 0; ks < 4; ++ks)
                    wf[ks] = *(const sv8*)&wpack[(((size_t)w * 12 + kx * 4 + ks) * 64 + lane) * 8];
#pragma unroll
                for (int ks = 0; ks < 4; ++ks)
#pragma unroll
                    for (int jj = 0; jj < 6; ++jj) {
                        sv8 bv = *(const sv8*)&smem[((yyv[jj] + kyv[ks]) * T1W + xxv[jj] + kx) * S1 + ci0v[ks]];
                        acc[jj] = __builtin_amdgcn_mfma_f32_16x16x32_bf16(wf[ks], bv, acc[jj], 0, 0, 0);
                    }
            }
            // epilogue A
            if (w < 2) {       // reset -> rh into tile2 (LDS only)
#pragma unroll
                for (int jj = 0; jj < 6; ++jj) {
                    int p2 = (half * 6 + jj) * 16 + m;
                    int yy = yyv[jj], xx = xxv[jj];
                    sv4 h4 = *(const sv4*)&smem[((yy + 1) * T1W + xx + 1) * S1 + 8 + co0g];
                    sv4 rh4;
#pragma unroll
                    for (int r = 0; r < 4; ++r) {
                        float gv = sigmoid_fast(acc[jj][r] + biasg[r]);
                        rh4[r] = (short)f2bf(gv * bf2f((u16)h4[r]));
                    }
                    if (p2 < 180)
                        *(sv4*)&smem[OFF2 + (yy * 18 + xx) * S2 + co0g] = rh4;
                }
            } else {           // update -> tileU (interior only)
                int u0 = co0g - 32;
#pragma unroll
                for (int jj = 0; jj < 6; ++jj) {
                    int p2 = (half * 6 + jj) * 16 + m;
                    int yy = yyv[jj], xx = xxv[jj];
                    u16 uv[4];
#pragma unroll
                    for (int r = 0; r < 4; ++r)
                        uv[r] = __half_as_ushort(__float2half(sigmoid_fast(acc[jj][r] + biasg[r])));
                    if (p2 < 180 && yy >= 1 && yy <= 8 && xx >= 1 && xx <= 16) {
                        int ub = OFFU + ((yy - 1) * 16 + (xx - 1)) * 33 + u0;
                        smem[ub] = uv[0]; smem[ub + 1] = uv[1];
                        smem[ub + 2] = uv[2]; smem[ub + 3] = uv[3];
                    }
                }
            }
        }
        __syncthreads();

        // ---- cand conv over interior 16x8 (4 rows per wave) + blend ----
        f32x4 a2[4];
#pragma unroll
        for (int k2 = 0; k2 < 4; ++k2) a2[k2] = (f32x4){0.f, 0.f, 0.f, 0.f};
#pragma unroll
        for (int kx = 0; kx < 3; ++kx) {
            sv8 wc[4];
#pragma unroll
            for (int ks = 0; ks < 4; ++ks)
                wc[ks] = *(const sv8*)&wpack[(((size_t)(4 + cg) * 12 + kx * 4 + ks) * 64 + lane) * 8];
#pragma unroll
            for (int ks = 0; ks < 4; ++ks)
#pragma unroll
                for (int k2 = 0; k2 < 4; ++k2) {
                    int j = nh * 4 + k2;
                    int a_x  = ((j + 1 + kyv[ks]) * T1W + m + 1 + kx) * S1;
                    int a_rh = OFF2 + ((j + kyv[ks]) * 18 + m + kx) * S2 + (ci0v[ks] - 8);
                    int addr = (ci0v[ks] == 0) ? a_x : a_rh;
                    sv4 lo = *(const sv4*)&smem[addr];
                    sv4 hi = *(const sv4*)&smem[addr + 4];
                    sv8 bv = __builtin_shufflevector(lo, hi, 0, 1, 2, 3, 4, 5, 6, 7);
                    a2[k2] = __builtin_amdgcn_mfma_f32_16x16x32_bf16(wc[ks], bv, a2[k2], 0, 0, 0);
                }
        }

#pragma unroll
        for (int k2 = 0; k2 < 4; ++k2) {
            int j = nh * 4 + k2;
            int gy = y0 + j, gx = x0 + m;
            int ctr = ((j + 2) * T1W + m + 2) * S1;
            sv4 h4 = *(const sv4*)&smem[ctr + 8 + co0c];
            int ub = OFFU + (j * 16 + m) * 33 + co0c;
            sv4 hn4;
#pragma unroll
            for (int r = 0; r < 4; ++r) {
                float cv   = tanh_fast(a2[k2][r] + biasc[r]);
                float uu   = __half2float(__ushort_as_half(smem[ub + r]));
                float hold = bf2f((u16)h4[r]);
                float hn = (1.f - uu) * hold + uu * cv;
                out[(((size_t)b * HID + co0c + r) * TT + t) * HW + (size_t)gy * WW + gx] = hn;
                hn4[r] = (short)f2bf(hn);
                if (t == TT - 1)
                    hlast[((size_t)b * HID + co0c + r) * HW + (size_t)gy * WW + gx] = hn;
            }
            *(sv4*)&smem[ctr + 8 + co0c] = hn4;   // persist h in LDS
            // 2-px interior border -> hG plane (t+1)&1, 8B relaxed atomic
            if (j <= 1 || j >= 6 || m <= 1 || m >= 14) {
                union { sv4 s; ull u; } cvt; cvt.s = hn4;
                __hip_atomic_store((ull*)&hGw[(size_t)(gy * WW + gx) * 32 + co0c],
                                   cvt.u, __ATOMIC_RELAXED, __HIP_MEMORY_SCOPE_AGENT);
            }
        }

        // all band stores reached the coherence point before flag post
        asm volatile("s_waitcnt vmcnt(0)" ::: "memory");
        __syncthreads();
        if (tid == 0)
            __hip_atomic_store(&flags[id * 32], t + 1, __ATOMIC_RELAXED,
                               __HIP_MEMORY_SCOPE_AGENT);
    }
}

extern "C" void kernel_launch(void* const* d_in, const int* in_sizes, int n_in,
                              void* d_out, int out_size, void* d_ws, size_t ws_size,
                              hipStream_t stream) {
    const float* x  = (const float*)d_in[0];
    const float* Wg = (const float*)d_in[1];
    const float* bg = (const float*)d_in[2];
    const float* Wc = (const float*)d_in[3];
    const float* bc = (const float*)d_in[4];

    float* out   = (float*)d_out;
    float* hlast = out + (size_t)BB * HID * TT * HW;

    const size_t PLANEB = (size_t)BB * HW * 32 * sizeof(u16);    // 8.39 MB
    const size_t PACKB  = (size_t)6 * 12 * 64 * 8 * sizeof(u16); // 73.7 KB
    const size_t FLAGB  = (size_t)NBLK * 32 * sizeof(int);       // 128 KB
    char* ws = (char*)d_ws;
    u16* hG    = (u16*)ws;                        // 2 planes
    u16* wpack = (u16*)(ws + 2 * PLANEB);
    int* flags = (int*)(ws + 2 * PLANEB + PACKB);
    u16* xbf   = (u16*)(ws + 2 * PLANEB + PACKB + FLAGB);

    pack_weights<<<(6 * 12 * 64 + 255) / 256, 256, 0, stream>>>(Wg, Wc, wpack);
    x_to_bf16<<<(BB * TT * HW) / 256, 256, 0, stream>>>(x, xbf);
    hipMemsetAsync(hG, 0, PLANEB, stream);        // plane 0 = h0 = 0
    hipMemsetAsync(flags, 0, FLAGB, stream);

    gru_persist<<<NBLK, 256, 0, stream>>>(xbf, wpack, bg, bc, hG, flags,
                                          out, hlast);
}

// Round 9
// 640.027 us; speedup vs baseline: 6.8300x; 2.3827x over previous
//
#include <hip/hip_runtime.h>
#include <hip/hip_bf16.h>
#include <hip/hip_fp16.h>
#include <cmath>

#define BB   8
#define CIN  8
#define TT   12
#define HH   128
#define WW   128
#define HID  32
#define CCOMB 40
#define HW   (HH * WW)
#define NBLK 512

// LDS (u16): tile1 [20x20 px][40] @0 (x ch0..7, h ch8..39);
// tile2 (rh, co 0..31) [18x18][36] @16000 ; tileU fp16 [256][36] @27664
// total 36880 u16 = 73,760 B -> 2 blocks/CU (147,520 <= 163,840)
#define S1    40
#define T1W   20
#define OFF2  16000
#define S2    36
#define OFFU  27664
#define SMEM_U16 36880

typedef __attribute__((ext_vector_type(8))) short sv8;
typedef __attribute__((ext_vector_type(4))) short sv4;
typedef __attribute__((ext_vector_type(4))) float f32x4;
typedef unsigned short u16;
typedef unsigned long long ull;

__device__ inline u16 f2bf(float f) {
    union { float f; unsigned u; } v; v.f = f;
    unsigned u = v.u;
    return (u16)((u + 0x7FFFu + ((u >> 16) & 1u)) >> 16);
}
__device__ inline float bf2f(u16 h) {
    union { unsigned u; float f; } v; v.u = ((unsigned)h) << 16; return v.f;
}
__device__ inline float sigmoid_fast(float x) { return 1.f / (1.f + __expf(-x)); }
__device__ inline float tanh_fast(float z) {
    float a = fabsf(z);
    float r = 1.f - 2.f / (__expf(2.f * a) + 1.f);
    return copysignf(r, z);
}

// 2-px outer ring of the 20x20 tile (144 px): i -> (r,c)
__device__ __forceinline__ void band_rc(int i, int& r, int& c) {
    if (i < 40)      { r = i / 20;            c = i % 20; }            // rows 0,1
    else if (i < 80) { int j = i - 40; r = 18 + j / 20; c = j % 20; }  // rows 18,19
    else             { int j = i - 80; r = 2 + (j >> 2);
                       int k = j & 3;  c = (k < 2) ? k : 16 + k; }     // cols 0,1,18,19
}

// ---------------------------------------------------------------------------
// weight pack: [Gall(6)][f=kx*4+ks (12)][lane(64)][8 bf16]
// ---------------------------------------------------------------------------
__device__ inline sv8 gather_wfrag(const float* __restrict__ W,
                                   int co, int g, int kx, int ks) {
    int k0 = ks * 32 + g * 8;
    sv8 f;
    if (k0 < 120) {
        int ky  = k0 / 40;
        int ci0 = k0 - ky * 40;
#pragma unroll
        for (int i = 0; i < 8; ++i)
            f[i] = (short)f2bf(W[(((size_t)co * CCOMB + ci0 + i) * 3 + ky) * 3 + kx]);
    } else {
#pragma unroll
        for (int i = 0; i < 8; ++i) f[i] = 0;
    }
    return f;
}

__global__ void pack_weights(const float* __restrict__ Wg,
                             const float* __restrict__ Wc,
                             u16* __restrict__ pack) {
    int tid = blockIdx.x * blockDim.x + threadIdx.x;
    if (tid >= 6 * 12 * 64) return;
    int lane = tid & 63;
    int f    = (tid >> 6) % 12;
    int Gall = tid / (12 * 64);
    int kx = f >> 2, ks = f & 3;
    int g = lane >> 4;
    sv8 v;
    if (Gall < 4) v = gather_wfrag(Wg, Gall * 16 + (lane & 15), g, kx, ks);
    else          v = gather_wfrag(Wc, (Gall - 4) * 16 + (lane & 15), g, kx, ks);
    *(sv8*)&pack[(size_t)tid * 8] = v;
}

__global__ __launch_bounds__(256) void x_to_bf16(const float* __restrict__ x,
                                                 u16* __restrict__ xbf) {
    int gid = blockIdx.x * 256 + threadIdx.x;
    if (gid >= BB * TT * HW) return;
    int p  = gid & (HW - 1);
    int bt = gid >> 14;
    int t = bt % TT, b = bt / TT;
    sv8 v;
#pragma unroll
    for (int c = 0; c < 8; ++c)
        v[c] = (short)f2bf(x[(((size_t)b * CIN + c) * TT + t) * HW + p]);
    *(sv8*)&xbf[(size_t)gid * 8] = v;
}

// ---------------------------------------------------------------------------
// Persistent GRU: 512 blocks (2/CU), 16x16 tile/block, weights in VGPRs.
// Fence-free p2p sync (relaxed device-scope atomics for all shared data).
// ---------------------------------------------------------------------------
__global__ __launch_bounds__(256, 2) void gru_persist(
    const u16* __restrict__ xbf, const u16* __restrict__ wpack,
    const float* __restrict__ bg, const float* __restrict__ bc,
    u16* __restrict__ hG, int* __restrict__ flags,
    float* __restrict__ out, float* __restrict__ hlast)
{
    __shared__ __align__(16) u16 smem[SMEM_U16];
    const int id = blockIdx.x;
    const int b = id & 7, tau = id >> 3;
    const int bx = tau & 7, by = tau >> 3;
    const int x0 = bx * 16, y0 = by * 16;
    const int tid = threadIdx.x, lane = tid & 63, w = tid >> 6;
    const int m = lane & 15, g = lane >> 4;

    // neighbor ids (8 dirs), -1 if outside image (8x8 tile grid)
    int nbr = -1;
    if (tid < 8) {
        const int dxs[8] = {-1, 0, 1, -1, 1, -1, 0, 1};
        const int dys[8] = {-1, -1, -1, 0, 0, 1, 1, 1};
        int nx = bx + dxs[tid], ny = by + dys[tid];
        if ((unsigned)nx < 8u && (unsigned)ny < 8u)
            nbr = ((ny * 8 + nx) * 8 + b);
    }

    int kyv[4], ci0v[4];
#pragma unroll
    for (int ks = 0; ks < 4; ++ks) {
        int k0 = ks * 32 + g * 8;
        kyv[ks] = 0; ci0v[ks] = 0;
        if (k0 < 120) { kyv[ks] = k0 / 40; ci0v[ks] = k0 - kyv[ks] * 40; }
    }

    // ---- weights: fully register-resident for the whole kernel ----
    const int cg = w & 1, half = w >> 1;
    sv8 wfg[12], wfc[12];
#pragma unroll
    for (int f = 0; f < 12; ++f) {
        wfg[f] = *(const sv8*)&wpack[(((size_t)w * 12 + f) * 64 + lane) * 8];
        wfc[f] = *(const sv8*)&wpack[(((size_t)(4 + cg) * 12 + f) * 64 + lane) * 8];
    }

    const int co0g = w * 16 + g * 4;          // gates co group
    const int co0c = cg * 16 + g * 4;         // cand co group
    float biasg[4], biasc[4];
#pragma unroll
    for (int r = 0; r < 4; ++r) { biasg[r] = bg[co0g + r]; biasc[r] = bc[co0c + r]; }

    // zero tile1 h slots (h0 = 0), 400 px x 4 q
    for (int i = tid; i < 1600; i += 256) {
        int px = i >> 2, q = i & 3;
        sv8 z = {};
        *(sv8*)&smem[px * S1 + 8 + q * 8] = z;
    }

    const u16* xbB = xbf + (size_t)b * TT * HW * 8;
    const size_t planeElems = (size_t)BB * HW * 32;

    for (int t = 0; t < TT; ++t) {
        const u16* hGr = hG + (size_t)(t & 1) * planeElems + (size_t)b * HW * 32;
        u16*       hGw = hG + (size_t)((t + 1) & 1) * planeElems + (size_t)b * HW * 32;

        // ---- stage x (400 px) — independent of neighbor progress ----
        const u16* xb = xbB + (size_t)t * HW * 8;
        for (int idx = tid; idx < 400; idx += 256) {
            int r = idx / 20, c = idx - r * 20;
            int gy = y0 + r - 2, gx = x0 + c - 2;
            sv8 v = {};
            if ((unsigned)gy < 128u && (unsigned)gx < 128u)
                v = *(const sv8*)&xb[(size_t)(gy * WW + gx) * 8];
            *(sv8*)&smem[idx * S1] = v;
        }

        // ---- wait for neighbors to finish step t-1 ----
        if (t > 0) {
            if (tid < 8 && nbr >= 0) {
                while (__hip_atomic_load(&flags[nbr * 32], __ATOMIC_RELAXED,
                                         __HIP_MEMORY_SCOPE_AGENT) < t)
                    __builtin_amdgcn_s_sleep(32);
            }
            __syncthreads();
        }

        // ---- stage h ring (144 px x 32ch) via 8B relaxed atomics ----
        for (int idx = tid; idx < 144 * 8; idx += 256) {
            int i = idx >> 3, q = idx & 7;
            int r, c; band_rc(i, r, c);
            int gy = y0 + r - 2, gx = x0 + c - 2;
            ull v = 0;
            if ((unsigned)gy < 128u && (unsigned)gx < 128u)
                v = __hip_atomic_load((const ull*)&hGr[(size_t)(gy * WW + gx) * 32 + q * 4],
                                      __ATOMIC_RELAXED, __HIP_MEMORY_SCOPE_AGENT);
            *(ull*)&smem[(r * T1W + c) * S1 + 8 + q * 4] = v;
        }
        __syncthreads();

        // ---- gates conv over 18x18 region (324 px = 3 batches x 7 n-tiles) ----
        for (int bt3 = 0; bt3 < 3; ++bt3) {
            int yyv[7], xxv[7]; bool val[7];
#pragma unroll
            for (int jj = 0; jj < 7; ++jj) {
                int p = (bt3 * 7 + jj) * 16 + m;
                val[jj] = (p < 324);
                int px = val[jj] ? p : 323;
                yyv[jj] = px / 18; xxv[jj] = px - yyv[jj] * 18;
            }
            f32x4 acc[7];
#pragma unroll
            for (int jj = 0; jj < 7; ++jj) acc[jj] = (f32x4){0.f, 0.f, 0.f, 0.f};
#pragma unroll
            for (int kx = 0; kx < 3; ++kx)
#pragma unroll
                for (int ks = 0; ks < 4; ++ks) {
#pragma unroll
                    for (int jj = 0; jj < 7; ++jj) {
                        sv8 bv = *(const sv8*)&smem[((yyv[jj] + kyv[ks]) * T1W + xxv[jj] + kx) * S1 + ci0v[ks]];
                        acc[jj] = __builtin_amdgcn_mfma_f32_16x16x32_bf16(wfg[kx * 4 + ks], bv, acc[jj], 0, 0, 0);
                    }
                }
            // epilogue A
            if (w < 2) {       // reset -> rh into tile2 (LDS only)
#pragma unroll
                for (int jj = 0; jj < 7; ++jj) {
                    int yy = yyv[jj], xx = xxv[jj];
                    sv4 h4 = *(const sv4*)&smem[((yy + 1) * T1W + xx + 1) * S1 + 8 + co0g];
                    sv4 rh4;
#pragma unroll
                    for (int r = 0; r < 4; ++r) {
                        float gv = sigmoid_fast(acc[jj][r] + biasg[r]);
                        rh4[r] = (short)f2bf(gv * bf2f((u16)h4[r]));
                    }
                    if (val[jj])
                        *(sv4*)&smem[OFF2 + (yy * 18 + xx) * S2 + co0g] = rh4;
                }
            } else {           // update -> tileU (interior 16x16 only)
                int u0 = co0g - 32;
#pragma unroll
                for (int jj = 0; jj < 7; ++jj) {
                    int yy = yyv[jj], xx = xxv[jj];
                    sv4 uv;
#pragma unroll
                    for (int r = 0; r < 4; ++r)
                        uv[r] = (short)__half_as_ushort(__float2half(sigmoid_fast(acc[jj][r] + biasg[r])));
                    if (val[jj] && yy >= 1 && yy <= 16 && xx >= 1 && xx <= 16)
                        *(sv4*)&smem[OFFU + ((yy - 1) * 16 + (xx - 1)) * S2 + u0] = uv;
                }
            }
        }
        __syncthreads();

        // ---- cand conv over interior 16x16 (8 rows per wave) + blend ----
        f32x4 a2[8];
#pragma unroll
        for (int jr = 0; jr < 8; ++jr) a2[jr] = (f32x4){0.f, 0.f, 0.f, 0.f};
#pragma unroll
        for (int kx = 0; kx < 3; ++kx)
#pragma unroll
            for (int ks = 0; ks < 4; ++ks) {
#pragma unroll
                for (int jr = 0; jr < 8; ++jr) {
                    int j = half * 8 + jr;
                    int a_x  = ((j + 1 + kyv[ks]) * T1W + m + 1 + kx) * S1;
                    int a_rh = OFF2 + ((j + kyv[ks]) * 18 + m + kx) * S2 + (ci0v[ks] - 8);
                    int addr = (ci0v[ks] == 0) ? a_x : a_rh;
                    sv4 lo = *(const sv4*)&smem[addr];
                    sv4 hi = *(const sv4*)&smem[addr + 4];
                    sv8 bv = __builtin_shufflevector(lo, hi, 0, 1, 2, 3, 4, 5, 6, 7);
                    a2[jr] = __builtin_amdgcn_mfma_f32_16x16x32_bf16(wfc[kx * 4 + ks], bv, a2[jr], 0, 0, 0);
                }
            }

#pragma unroll
        for (int jr = 0; jr < 8; ++jr) {
            int j = half * 8 + jr;
            int gy = y0 + j, gx = x0 + m;
            int ctr = ((j + 2) * T1W + m + 2) * S1;
            sv4 h4 = *(const sv4*)&smem[ctr + 8 + co0c];
            int ub = OFFU + (j * 16 + m) * S2 + co0c;
            sv4 hn4;
#pragma unroll
            for (int r = 0; r < 4; ++r) {
                float cv   = tanh_fast(a2[jr][r] + biasc[r]);
                float uu   = __half2float(__ushort_as_half((u16)smem[ub + r]));
                float hold = bf2f((u16)h4[r]);
                float hn = (1.f - uu) * hold + uu * cv;
                out[(((size_t)b * HID + co0c + r) * TT + t) * HW + (size_t)gy * WW + gx] = hn;
                hn4[r] = (short)f2bf(hn);
                if (t == TT - 1)
                    hlast[((size_t)b * HID + co0c + r) * HW + (size_t)gy * WW + gx] = hn;
            }
            *(sv4*)&smem[ctr + 8 + co0c] = hn4;   // persist h in LDS
            // 2-px interior border -> hG plane (t+1)&1, 8B relaxed atomic
            if (j <= 1 || j >= 14 || m <= 1 || m >= 14) {
                union { sv4 s; ull u; } cvt; cvt.s = hn4;
                __hip_atomic_store((ull*)&hGw[(size_t)(gy * WW + gx) * 32 + co0c],
                                   cvt.u, __ATOMIC_RELAXED, __HIP_MEMORY_SCOPE_AGENT);
            }
        }

        // all band stores at coherence point before flag post
        asm volatile("s_waitcnt vmcnt(0)" ::: "memory");
        __syncthreads();
        if (tid == 0)
            __hip_atomic_store(&flags[id * 32], t + 1, __ATOMIC_RELAXED,
                               __HIP_MEMORY_SCOPE_AGENT);
    }
}

extern "C" void kernel_launch(void* const* d_in, const int* in_sizes, int n_in,
                              void* d_out, int out_size, void* d_ws, size_t ws_size,
                              hipStream_t stream) {
    const float* x  = (const float*)d_in[0];
    const float* Wg = (const float*)d_in[1];
    const float* bg = (const float*)d_in[2];
    const float* Wc = (const float*)d_in[3];
    const float* bc = (const float*)d_in[4];

    float* out   = (float*)d_out;
    float* hlast = out + (size_t)BB * HID * TT * HW;

    const size_t PLANEB = (size_t)BB * HW * 32 * sizeof(u16);    // 8.39 MB
    const size_t PACKB  = (size_t)6 * 12 * 64 * 8 * sizeof(u16); // 73.7 KB
    const size_t FLAGB  = (size_t)NBLK * 32 * sizeof(int);       // 64 KB
    char* ws = (char*)d_ws;
    u16* hG    = (u16*)ws;                        // 2 planes
    u16* wpack = (u16*)(ws + 2 * PLANEB);
    int* flags = (int*)(ws + 2 * PLANEB + PACKB);
    u16* xbf   = (u16*)(ws + 2 * PLANEB + PACKB + FLAGB);

    pack_weights<<<(6 * 12 * 64 + 255) / 256, 256, 0, stream>>>(Wg, Wc, wpack);
    x_to_bf16<<<(BB * TT * HW) / 256, 256, 0, stream>>>(x, xbf);
    hipMemsetAsync(hG, 0, PLANEB, stream);        // plane 0 = h0 = 0
    hipMemsetAsync(flags, 0, FLAGB, stream);

    gru_persist<<<NBLK, 256, 0, stream>>>(xbf, wpack, bg, bc, hG, flags,
                                          out, hlast);
}